// Round 18
// baseline (338.651 us; speedup 1.0000x reference)
//
#include <hip/hip_runtime.h>
#include <math.h>

// Problem constants (match reference)
#define B_TOK 16384
#define H_DIM 2048
#define NE    8
#define TOPK  2
#define HFD   512

#define BK 64
#define NKSTEP (H_DIM / BK)   // 32
#define PT256 64              // worst-case 256-pos tiles per expert
#define PROWS 35840           // padded P rows total (8 experts, 256-padded)

// Workspace layout (bytes)
static constexpr size_t OFF_COUNTS = 0;           // 32 B
static constexpr size_t OFF_CBASE  = 128;         // cbase[8] + cpad[8]
static constexpr size_t OFF_BUCKET = 1024;        // 512 KB
static constexpr size_t OFF_WSLOT  = 525312;      // 128 KB
static constexpr size_t OFF_ROUTE  = 656384;      // 64 KB
static constexpr size_t OFF_INV    = 721920;      // 128 KB
static constexpr size_t OFF_WGT    = 1u << 20;    // 512 KB
static constexpr size_t OFF_P2     = 1572864;     // 2 x 35840 floats = 287 KB
static constexpr size_t OFF_W1H    = 4u << 20;    // 16 MB -> ends 20 MB
static constexpr size_t OFF_XB     = 20971520;    // 64 MB bf16 x -> ends 84 MB

typedef short bfrag __attribute__((ext_vector_type(8)));   // 8 bf16 (4 VGPR)
typedef float facc  __attribute__((ext_vector_type(16)));  // 32x32 accum

__device__ inline unsigned short f2bf(float f) {
    union { float f; unsigned u; } v; v.f = f;
    unsigned r = v.u + 0x7FFFu + ((v.u >> 16) & 1u);
    return (unsigned short)(r >> 16);
}
__device__ inline unsigned pack2(float lo, float hi) {
    return (unsigned)f2bf(lo) | ((unsigned)f2bf(hi) << 16);
}

__device__ __forceinline__ void gload_lds16(const void* g, void* l) {
    __builtin_amdgcn_global_load_lds(
        (const __attribute__((address_space(1))) unsigned int*)g,
        (__attribute__((address_space(3))) unsigned int*)l, 16, 0, 0);
}

// ---------------------------------------------------------------------------
// Transpose gate weights: Wg [H][E] -> 8 replicas of WgT [E][H].
// ---------------------------------------------------------------------------
__global__ __launch_bounds__(256)
void wg_transpose_kernel(const float* __restrict__ Wg,
                         float* __restrict__ WgT)
{
    const int t = threadIdx.x;
    #pragma unroll
    for (int rep = 0; rep < H_DIM / 256; ++rep) {
        const int h = rep * 256 + t;
        const float4 a = *reinterpret_cast<const float4*>(Wg + (size_t)h * NE);
        const float4 b = *reinterpret_cast<const float4*>(Wg + (size_t)h * NE + 4);
        #pragma unroll
        for (int rr = 0; rr < 8; ++rr) {
            float* W = WgT + (size_t)rr * (NE * H_DIM);
            W[0 * H_DIM + h] = a.x;  W[1 * H_DIM + h] = a.y;
            W[2 * H_DIM + h] = a.z;  W[3 * H_DIM + h] = a.w;
            W[4 * H_DIM + h] = b.x;  W[5 * H_DIM + h] = b.y;
            W[6 * H_DIM + h] = b.z;  W[7 * H_DIM + h] = b.w;
        }
    }
}

// ---------------------------------------------------------------------------
// Prep W1: [E][H][HF] fp32 -> per-(e, f-half fn) k-slot-major bf16 images:
//   W1h[(e*2+fn)*32 + kstep][slot(8)][f'(256)][j(8)]  (32 KB per image)
// element k = kstep*64 + slot*8 + j, f = fn*256 + f'. Each image is exactly
// one expert-kernel A-stage (linear copy, conflict-free k-slot-major reads).
// ---------------------------------------------------------------------------
__global__ __launch_bounds__(256)
void prep_w1_kernel(const float* __restrict__ W1,
                    unsigned short* __restrict__ W1h)
{
    const int e     = blockIdx.x >> 5;
    const int kstep = blockIdx.x & 31;
    const int tid   = threadIdx.x;

    const float* src = W1 + ((size_t)e * H_DIM + kstep * BK) * HFD;

    #pragma unroll
    for (int slot = 0; slot < 8; ++slot) {
        #pragma unroll
        for (int fn = 0; fn < 2; ++fn) {
            const int f = fn * 256 + tid;
            float v[8];
            #pragma unroll
            for (int j = 0; j < 8; ++j)
                v[j] = src[(size_t)(slot * 8 + j) * HFD + f];   // lane-coalesced
            uint4 p;
            p.x = pack2(v[0], v[1]); p.y = pack2(v[2], v[3]);
            p.z = pack2(v[4], v[5]); p.w = pack2(v[6], v[7]);
            *reinterpret_cast<uint4*>(
                W1h + ((size_t)((e * 2 + fn) * 32 + kstep)) * 16384
                    + (slot * 256 + tid) * 8) = p;
        }
    }
}

// ---------------------------------------------------------------------------
// Gate logits: 256 blocks x 64 tokens; WgT staged once into LDS.
// Also converts x rows to bf16 (xb), the expert kernel's B source.
// ---------------------------------------------------------------------------
__global__ __launch_bounds__(256)
void gate_logits_kernel(const float* __restrict__ x,
                        const float* __restrict__ WgT,
                        const float* __restrict__ bg,
                        float* __restrict__ out_logits,
                        float* __restrict__ wslot,
                        int*   __restrict__ route,
                        unsigned short* __restrict__ xb)
{
    __shared__ float Wlds[NE * H_DIM];   // 64 KB

    const int tid = threadIdx.x;
    const float* Wsrc = WgT + (size_t)(blockIdx.x & 7) * (NE * H_DIM);
    #pragma unroll
    for (int i = 0; i < (NE * H_DIM) / (256 * 4); ++i) {
        const int idx = (i * 256 + tid) * 4;
        *reinterpret_cast<float4*>(&Wlds[idx]) =
            *reinterpret_cast<const float4*>(Wsrc + idx);
    }
    __syncthreads();

    const int w = tid >> 6, l = tid & 63;
    const int tbase = blockIdx.x * 64 + w * 16;

    for (int pass = 0; pass < 4; ++pass) {
        const int t0 = tbase + pass * 4;
        float acc[4][NE];
        #pragma unroll
        for (int j = 0; j < 4; ++j)
            #pragma unroll
            for (int e = 0; e < NE; ++e) acc[j][e] = 0.f;

        for (int i = 0; i < 8; ++i) {
            const int h = i * 256 + 4 * l;
            float4 xv[4];
            #pragma unroll
            for (int j = 0; j < 4; ++j)
                xv[j] = *reinterpret_cast<const float4*>(
                    x + (size_t)(t0 + j) * H_DIM + h);
            #pragma unroll
            for (int j = 0; j < 4; ++j) {
                uint2 pk;
                pk.x = pack2(xv[j].x, xv[j].y);
                pk.y = pack2(xv[j].z, xv[j].w);
                *reinterpret_cast<uint2*>(xb + (size_t)(t0 + j) * H_DIM + h) = pk;
            }
            #pragma unroll
            for (int e = 0; e < NE; ++e) {
                const float4 wv = *reinterpret_cast<const float4*>(&Wlds[e * H_DIM + h]);
                #pragma unroll
                for (int j = 0; j < 4; ++j)
                    acc[j][e] += xv[j].x * wv.x + xv[j].y * wv.y
                               + xv[j].z * wv.z + xv[j].w * wv.w;
            }
        }

        #pragma unroll
        for (int j = 0; j < 4; ++j)
            #pragma unroll
            for (int e = 0; e < NE; ++e)
                #pragma unroll
                for (int off = 32; off > 0; off >>= 1)
                    acc[j][e] += __shfl_xor(acc[j][e], off, 64);

        if (l == 0) {
            #pragma unroll
            for (int j = 0; j < 4; ++j) {
                const int tok = t0 + j;
                float lg[NE];
                #pragma unroll
                for (int e = 0; e < NE; ++e) lg[e] = acc[j][e] + bg[e];

                float4* lo = reinterpret_cast<float4*>(out_logits + (size_t)tok * NE);
                lo[0] = make_float4(lg[0], lg[1], lg[2], lg[3]);
                lo[1] = make_float4(lg[4], lg[5], lg[6], lg[7]);

                int i0 = 0; float v0 = lg[0];
                #pragma unroll
                for (int e = 1; e < NE; ++e)
                    if (lg[e] > v0) { v0 = lg[e]; i0 = e; }
                int i1 = -1; float v1 = -3.4e38f;
                #pragma unroll
                for (int e = 0; e < NE; ++e)
                    if (e != i0 && lg[e] > v1) { v1 = lg[e]; i1 = e; }

                const float w0 = 1.f / (1.f + expf(v1 - v0));
                wslot[tok * 2]     = w0;
                wslot[tok * 2 + 1] = 1.f - w0;
                route[tok] = i0 | (i1 << 8);
            }
        }
    }
}

// ---------------------------------------------------------------------------
// Route/bucket: LDS-aggregated histogram; 8 global atomics per block.
// ---------------------------------------------------------------------------
__global__ __launch_bounds__(1024)
void route_kernel(const int* __restrict__ route,
                  int* __restrict__ counts,
                  int* __restrict__ bucket)
{
    __shared__ int lcnt[NE];
    __shared__ int lbase[NE];
    const int tid = threadIdx.x;
    const int tok = blockIdx.x * 1024 + tid;

    if (tid < NE) lcnt[tid] = 0;
    __syncthreads();

    const int rt = route[tok];
    const int i0 = rt & 255;
    const int i1 = rt >> 8;
    const int r0 = atomicAdd(&lcnt[i0], 1);
    const int r1 = atomicAdd(&lcnt[i1], 1);
    __syncthreads();

    if (tid < NE) lbase[tid] = atomicAdd(&counts[tid], lcnt[tid]);
    __syncthreads();

    bucket[i0 * B_TOK + lbase[i0] + r0] = tok * 2;
    bucket[i1 * B_TOK + lbase[i1] + r1] = tok * 2 + 1;
}

// ---------------------------------------------------------------------------
// Prefix: cbase[e] = row base; cpad[e] = count padded to 256.
// ---------------------------------------------------------------------------
__global__ void prefix_kernel(const int* __restrict__ counts,
                              int* __restrict__ cbase)
{
    if (threadIdx.x == 0 && blockIdx.x == 0) {
        int acc = 0;
        for (int e = 0; e < NE; ++e) {
            const int cp = ((counts[e] + 255) >> 8) << 8;
            cbase[e]      = acc;
            cbase[NE + e] = cp;
            acc += cp;
        }
    }
}

// ---------------------------------------------------------------------------
// invfill: inv[entry] = global P row for each bucket slot.
// ---------------------------------------------------------------------------
__global__ __launch_bounds__(256)
void invfill_kernel(const int* __restrict__ bucket,
                    const int* __restrict__ counts,
                    const int* __restrict__ cbase,
                    int* __restrict__ inv)
{
    const int e   = blockIdx.x & 7;
    const int pos = (blockIdx.x >> 3) * 256 + threadIdx.x;
    if (pos < counts[e]) inv[bucket[e * B_TOK + pos]] = cbase[e] + pos;
}

// ---------------------------------------------------------------------------
// Expert MFMA (256x256 tile, T3 single-barrier 2-phase):
// block = (e, f-half fn (256 f), 256-pos tile); 512 thr / 8 waves;
// wave = (wm: 128-f half) x (wn: 64-pos quarter); acc[4][2] = 128 VGPR.
// Per K-step (BK=64): STAGE(kk+1) into the other buffer [8 gload_lds16 per
// thread: 4 A linear from the 32 KB k-slot W-image + 4 B full-line gather
// from xb, chunk-XOR pre-swizzled source], then COMPUTE(kk) [24 ds_read +
// 32 MFMA under setprio], then ONE __syncthreads (vmcnt drain + barrier).
// Reads of buf[cur] precede the barrier; its overwrite follows it -> safe.
// 130 KB LDS -> 1 block/CU, 2 waves/SIMD. Deterministic P2 partials.
// ---------------------------------------------------------------------------
__global__ __launch_bounds__(512, 1)
void expert_mfma_kernel(const unsigned short* __restrict__ xb,
                        const unsigned short* __restrict__ W1h,
                        const float* __restrict__ b1,
                        const float* __restrict__ W2,
                        const int* __restrict__ counts,
                        const int* __restrict__ cbase,
                        const int* __restrict__ bucket,
                        float* __restrict__ P2)
{
    const int e  = blockIdx.x & 7;
    const int r  = blockIdx.x >> 3;
    const int fn = r & 1;
    const int pt = r >> 1;
    const int n  = counts[e];
    const int pos0 = pt * 256;
    if (pos0 >= n) return;
    const int nt = min(256, n - pos0);
    const int cb = cbase[e];

    __shared__ unsigned short Ab[2][16384];   // [slot8][f'256][j8]   32 KB each
    __shared__ unsigned short Bb[2][16384];   // [row256][chunk8^][8] 32 KB each
    __shared__ float o_part[2][256];          // 2 KB

    const int tid = threadIdx.x;
    const int w   = tid >> 6;
    const int l   = tid & 63;
    const int lo5 = l & 31;
    const int hi  = l >> 5;
    const int wm  = w & 1;      // f half (128 rows)
    const int wn  = w >> 1;     // pos quarter (64 cols)

    const unsigned short* Aimg = W1h + (size_t)((e * 2 + fn) * 32) * 16384;

    // B gather bases: 4 (row, chunk') units per thread; source chunk
    // pre-XORed (chunk' ^ (row&7)) so read-side XOR retrieves k-chunks.
    const int u0 = 0 * 512 + tid, u1 = 1 * 512 + tid,
              u2 = 2 * 512 + tid, u3 = 3 * 512 + tid;
    const int r0 = u0 >> 3, r1 = u1 >> 3, r2 = u2 >> 3, r3 = u3 >> 3;
    const int t0 = bucket[e * B_TOK + min(pos0 + r0, n - 1)] >> 1;
    const int t1 = bucket[e * B_TOK + min(pos0 + r1, n - 1)] >> 1;
    const int t2 = bucket[e * B_TOK + min(pos0 + r2, n - 1)] >> 1;
    const int t3 = bucket[e * B_TOK + min(pos0 + r3, n - 1)] >> 1;
    const unsigned short* xs0 = xb + (size_t)t0 * H_DIM + (((u0 & 7) ^ (r0 & 7)) * 8);
    const unsigned short* xs1 = xb + (size_t)t1 * H_DIM + (((u1 & 7) ^ (r1 & 7)) * 8);
    const unsigned short* xs2 = xb + (size_t)t2 * H_DIM + (((u2 & 7) ^ (r2 & 7)) * 8);
    const unsigned short* xs3 = xb + (size_t)t3 * H_DIM + (((u3 & 7) ^ (r3 & 7)) * 8);
    const int o0 = u0 * 8, o1 = u1 * 8, o2 = u2 * 8, o3 = u3 * 8;

    facc acc[4][2];
    #pragma unroll
    for (int m = 0; m < 4; ++m)
        #pragma unroll
        for (int nb = 0; nb < 2; ++nb)
            #pragma unroll
            for (int q = 0; q < 16; ++q) acc[m][nb][q] = 0.f;

    // 4 A linear + 4 B gather loads per thread per step.
    #define STAGE(KK, BUF) do {                                                \
        const unsigned short* as_ = Aimg + (size_t)(KK) * 16384;               \
        gload_lds16(as_ + o0, &Ab[BUF][o0]);                                   \
        gload_lds16(as_ + o1, &Ab[BUF][o1]);                                   \
        gload_lds16(as_ + o2, &Ab[BUF][o2]);                                   \
        gload_lds16(as_ + o3, &Ab[BUF][o3]);                                   \
        gload_lds16(xs0 + (KK) * BK, &Bb[BUF][o0]);                            \
        gload_lds16(xs1 + (KK) * BK, &Bb[BUF][o1]);                            \
        gload_lds16(xs2 + (KK) * BK, &Bb[BUF][o2]);                            \
        gload_lds16(xs3 + (KK) * BK, &Bb[BUF][o3]);                            \
    } while (0)

    #define COMPUTE(BUF) do {                                                  \
        _Pragma("unroll")                                                      \
        for (int ks = 0; ks < 4; ++ks) {                                       \
            const int slot = ks * 2 + hi;                                      \
            bfrag a[4], bb[2];                                                 \
            _Pragma("unroll")                                                  \
            for (int m = 0; m < 4; ++m)                                        \
                a[m] = *reinterpret_cast<const bfrag*>(                        \
                    &Ab[BUF][(slot * 256 + wm * 128 + m * 32 + lo5) * 8]);     \
            _Pragma("unroll")                                                  \
            for (int nb = 0; nb < 2; ++nb) {                                   \
                const int row = wn * 64 + nb * 32 + lo5;                       \
                const int ch  = slot ^ (row & 7);                              \
                bb[nb] = *reinterpret_cast<const bfrag*>(                      \
                    &Bb[BUF][(row * 8 + ch) * 8]);                             \
            }                                                                  \
            _Pragma("unroll")                                                  \
            for (int m = 0; m < 4; ++m)                                        \
                _Pragma("unroll")                                              \
                for (int nb = 0; nb < 2; ++nb)                                 \
                    acc[m][nb] = __builtin_amdgcn_mfma_f32_32x32x16_bf16(      \
                        a[m], bb[nb], acc[m][nb], 0, 0, 0);                    \
        }                                                                      \
    } while (0)

    STAGE(0, 0);
    __syncthreads();                       // buf0 staged (vmcnt drained)

    for (int kk = 0; kk < NKSTEP; ++kk) {
        const int cur = kk & 1;
        if (kk + 1 < NKSTEP) STAGE(kk + 1, cur ^ 1);   // issue loads FIRST
        __builtin_amdgcn_s_setprio(1);
        COMPUTE(cur);                                  // ds_read + MFMA
        __builtin_amdgcn_s_setprio(0);
        __syncthreads();   // ONE barrier/step: drains stage, seals reads
    }
    #undef STAGE
    #undef COMPUTE

    // Epilogue: bias + exact GELU + W2 dot; reduce over this block's 256 f.
    const float* b1e = b1 + e * HFD + fn * 256;
    const float* W2e = W2 + e * HFD + fn * 256;
    const float kInvSqrt2 = 0.70710678118654752f;

    float po0 = 0.f, po1 = 0.f;
    #pragma unroll
    for (int m = 0; m < 4; ++m) {
        const int base = wm * 128 + m * 32 + 4 * hi;
        #pragma unroll
        for (int q = 0; q < 16; ++q) {
            const int frow = base + (q & 3) + 8 * (q >> 2);
            const float bv = b1e[frow];
            const float wv = W2e[frow];
            const float h0 = acc[m][0][q] + bv;
            const float h1 = acc[m][1][q] + bv;
            po0 += 0.5f * h0 * (1.f + erff(h0 * kInvSqrt2)) * wv;
            po1 += 0.5f * h1 * (1.f + erff(h1 * kInvSqrt2)) * wv;
        }
    }
    po0 += __shfl_xor(po0, 32, 64);
    po1 += __shfl_xor(po1, 32, 64);

    if (hi == 0) {
        o_part[wm][wn * 64 + lo5]      = po0;
        o_part[wm][wn * 64 + 32 + lo5] = po1;
    }
    __syncthreads();

    if (tid < nt)
        P2[(size_t)fn * PROWS + cb + pos0 + tid] =
            o_part[0][tid] + o_part[1][tid];
}

// ---------------------------------------------------------------------------
// Combine: out[t] = w0*(P2[0][g0]+P2[1][g0]) + w1*(...). Deterministic.
// ---------------------------------------------------------------------------
__global__ __launch_bounds__(256)
void combine_kernel(const int* __restrict__ inv,
                    const float* __restrict__ P2,
                    const float* __restrict__ wslot,
                    float* __restrict__ out_scores)
{
    const int t = blockIdx.x * 256 + threadIdx.x;
    if (t >= B_TOK) return;
    const int g0 = inv[2 * t];
    const int g1 = inv[2 * t + 1];
    const float s0 = P2[g0] + P2[PROWS + g0];
    const float s1 = P2[g1] + P2[PROWS + g1];
    out_scores[t] = wslot[2 * t] * s0 + wslot[2 * t + 1] * s1;
}

// ---------------------------------------------------------------------------
extern "C" void kernel_launch(void* const* d_in, const int* in_sizes, int n_in,
                              void* d_out, int out_size, void* d_ws, size_t ws_size,
                              hipStream_t stream)
{
    const float* x  = (const float*)d_in[0];
    const float* W1 = (const float*)d_in[1];
    const float* b1 = (const float*)d_in[2];
    const float* W2 = (const float*)d_in[3];
    const float* Wg = (const float*)d_in[4];
    const float* bg = (const float*)d_in[5];

    float* out        = (float*)d_out;
    float* out_scores = out;            // [B, 1]
    float* out_logits = out + B_TOK;    // [B, E]

    char* ws = (char*)d_ws;
    int*            counts = (int*)           (ws + OFF_COUNTS);
    int*            cbase  = (int*)           (ws + OFF_CBASE);
    int*            bucket = (int*)           (ws + OFF_BUCKET);
    float*          wslot  = (float*)         (ws + OFF_WSLOT);
    int*            route  = (int*)           (ws + OFF_ROUTE);
    int*            inv    = (int*)           (ws + OFF_INV);
    float*          WgT    = (float*)         (ws + OFF_WGT);
    float*          P2     = (float*)         (ws + OFF_P2);
    unsigned short* W1h    = (unsigned short*)(ws + OFF_W1H);
    unsigned short* xb     = (unsigned short*)(ws + OFF_XB);

    hipMemsetAsync(counts, 0, NE * sizeof(int), stream);

    wg_transpose_kernel<<<1, 256, 0, stream>>>(Wg, WgT);

    prep_w1_kernel<<<NE * NKSTEP, 256, 0, stream>>>(W1, W1h);

    gate_logits_kernel<<<B_TOK / 64, 256, 0, stream>>>(x, WgT, bg, out_logits,
                                                       wslot, route, xb);

    route_kernel<<<B_TOK / 1024, 1024, 0, stream>>>(route, counts, bucket);

    prefix_kernel<<<1, 64, 0, stream>>>(counts, cbase);

    invfill_kernel<<<NE * (B_TOK / 256), 256, 0, stream>>>(bucket, counts,
                                                           cbase, inv);

    expert_mfma_kernel<<<NE * 2 * PT256, 512, 0, stream>>>(
        xb, W1h, b1, W2, counts, cbase, bucket, P2);

    combine_kernel<<<B_TOK / 256, 256, 0, stream>>>(inv, P2, wslot, out_scores);
}

// Round 19
// 266.068 us; speedup vs baseline: 1.2728x; 1.2728x over previous
//
#include <hip/hip_runtime.h>
#include <math.h>

// Problem constants (match reference)
#define B_TOK 16384
#define H_DIM 2048
#define NE    8
#define TOPK  2
#define HFD   512

#define BK 32
#define NKSTEP (H_DIM / BK)   // 64
#define PT64  256             // worst-case 64-pos tiles per expert
#define PROWS 33792           // padded P rows total (8 experts, 128-padded)

// Workspace layout (bytes)
static constexpr size_t OFF_COUNTS = 0;
static constexpr size_t OFF_CBASE  = 128;
static constexpr size_t OFF_BUCKET = 1024;        // 512 KB
static constexpr size_t OFF_WSLOT  = 525312;      // 128 KB
static constexpr size_t OFF_ROUTE  = 656384;      // 64 KB
static constexpr size_t OFF_INV    = 721920;      // 128 KB
static constexpr size_t OFF_WGT    = 1u << 20;    // 512 KB
static constexpr size_t OFF_P2     = 1572864;     // 2 x 33792 floats
static constexpr size_t OFF_W1H    = 4u << 20;    // 16 MB -> ends 20 MB
static constexpr size_t OFF_XB     = 20971520;    // 64 MB bf16 x

typedef short bfrag __attribute__((ext_vector_type(8)));   // 8 bf16 (4 VGPR)
typedef float facc  __attribute__((ext_vector_type(16)));  // 32x32 accum

__device__ inline unsigned short f2bf(float f) {
    union { float f; unsigned u; } v; v.f = f;
    unsigned r = v.u + 0x7FFFu + ((v.u >> 16) & 1u);
    return (unsigned short)(r >> 16);
}
__device__ inline unsigned pack2(float lo, float hi) {
    return (unsigned)f2bf(lo) | ((unsigned)f2bf(hi) << 16);
}

__device__ __forceinline__ void gload_lds16(const void* g, void* l) {
    __builtin_amdgcn_global_load_lds(
        (const __attribute__((address_space(1))) unsigned int*)g,
        (__attribute__((address_space(3))) unsigned int*)l, 16, 0, 0);
}

// ---------------------------------------------------------------------------
// Transpose gate weights: Wg [H][E] -> 8 replicas of WgT [E][H].
// ---------------------------------------------------------------------------
__global__ __launch_bounds__(256)
void wg_transpose_kernel(const float* __restrict__ Wg,
                         float* __restrict__ WgT)
{
    const int t = threadIdx.x;
    #pragma unroll
    for (int rep = 0; rep < H_DIM / 256; ++rep) {
        const int h = rep * 256 + t;
        const float4 a = *reinterpret_cast<const float4*>(Wg + (size_t)h * NE);
        const float4 b = *reinterpret_cast<const float4*>(Wg + (size_t)h * NE + 4);
        #pragma unroll
        for (int rr = 0; rr < 8; ++rr) {
            float* W = WgT + (size_t)rr * (NE * H_DIM);
            W[0 * H_DIM + h] = a.x;  W[1 * H_DIM + h] = a.y;
            W[2 * H_DIM + h] = a.z;  W[3 * H_DIM + h] = a.w;
            W[4 * H_DIM + h] = b.x;  W[5 * H_DIM + h] = b.y;
            W[6 * H_DIM + h] = b.z;  W[7 * H_DIM + h] = b.w;
        }
    }
}

// ---------------------------------------------------------------------------
// Prep W1: [E][H][HF] fp32 -> per-(e, f-half fh) k-slot-major bf16 images:
//   W1h[(e*2+fh)*64 + kstep][slot(4)][f'(256)][j(8)]  (16 KB per image)
// k = kstep*32 + slot*8 + j, f = fh*256 + f'.
// ---------------------------------------------------------------------------
__global__ __launch_bounds__(256)
void prep_w1_kernel(const float* __restrict__ W1,
                    unsigned short* __restrict__ W1h)
{
    const int e     = blockIdx.x >> 6;
    const int kstep = blockIdx.x & 63;
    const int tid   = threadIdx.x;

    const float* src = W1 + ((size_t)e * H_DIM + kstep * BK) * HFD;

    #pragma unroll
    for (int s = 0; s < 4; ++s) {
        #pragma unroll
        for (int fh = 0; fh < 2; ++fh) {
            const int f = fh * 256 + tid;
            float v[8];
            #pragma unroll
            for (int j = 0; j < 8; ++j)
                v[j] = src[(size_t)(s * 8 + j) * HFD + f];   // lane-coalesced
            uint4 p;
            p.x = pack2(v[0], v[1]); p.y = pack2(v[2], v[3]);
            p.z = pack2(v[4], v[5]); p.w = pack2(v[6], v[7]);
            *reinterpret_cast<uint4*>(
                W1h + ((size_t)((e * 2 + fh) * 64 + kstep)) * 8192
                    + (s * 256 + tid) * 8) = p;
        }
    }
}

// ---------------------------------------------------------------------------
// Gate logits: 256 blocks x 64 tokens; WgT staged once into LDS.
// Also converts x rows to bf16 (xb), the expert kernel's B source.
// ---------------------------------------------------------------------------
__global__ __launch_bounds__(256)
void gate_logits_kernel(const float* __restrict__ x,
                        const float* __restrict__ WgT,
                        const float* __restrict__ bg,
                        float* __restrict__ out_logits,
                        float* __restrict__ wslot,
                        int*   __restrict__ route,
                        unsigned short* __restrict__ xb)
{
    __shared__ float Wlds[NE * H_DIM];   // 64 KB

    const int tid = threadIdx.x;
    const float* Wsrc = WgT + (size_t)(blockIdx.x & 7) * (NE * H_DIM);
    #pragma unroll
    for (int i = 0; i < (NE * H_DIM) / (256 * 4); ++i) {
        const int idx = (i * 256 + tid) * 4;
        *reinterpret_cast<float4*>(&Wlds[idx]) =
            *reinterpret_cast<const float4*>(Wsrc + idx);
    }
    __syncthreads();

    const int w = tid >> 6, l = tid & 63;
    const int tbase = blockIdx.x * 64 + w * 16;

    for (int pass = 0; pass < 4; ++pass) {
        const int t0 = tbase + pass * 4;
        float acc[4][NE];
        #pragma unroll
        for (int j = 0; j < 4; ++j)
            #pragma unroll
            for (int e = 0; e < NE; ++e) acc[j][e] = 0.f;

        for (int i = 0; i < 8; ++i) {
            const int h = i * 256 + 4 * l;
            float4 xv[4];
            #pragma unroll
            for (int j = 0; j < 4; ++j)
                xv[j] = *reinterpret_cast<const float4*>(
                    x + (size_t)(t0 + j) * H_DIM + h);
            #pragma unroll
            for (int j = 0; j < 4; ++j) {
                uint2 pk;
                pk.x = pack2(xv[j].x, xv[j].y);
                pk.y = pack2(xv[j].z, xv[j].w);
                *reinterpret_cast<uint2*>(xb + (size_t)(t0 + j) * H_DIM + h) = pk;
            }
            #pragma unroll
            for (int e = 0; e < NE; ++e) {
                const float4 wv = *reinterpret_cast<const float4*>(&Wlds[e * H_DIM + h]);
                #pragma unroll
                for (int j = 0; j < 4; ++j)
                    acc[j][e] += xv[j].x * wv.x + xv[j].y * wv.y
                               + xv[j].z * wv.z + xv[j].w * wv.w;
            }
        }

        #pragma unroll
        for (int j = 0; j < 4; ++j)
            #pragma unroll
            for (int e = 0; e < NE; ++e)
                #pragma unroll
                for (int off = 32; off > 0; off >>= 1)
                    acc[j][e] += __shfl_xor(acc[j][e], off, 64);

        if (l == 0) {
            #pragma unroll
            for (int j = 0; j < 4; ++j) {
                const int tok = t0 + j;
                float lg[NE];
                #pragma unroll
                for (int e = 0; e < NE; ++e) lg[e] = acc[j][e] + bg[e];

                float4* lo = reinterpret_cast<float4*>(out_logits + (size_t)tok * NE);
                lo[0] = make_float4(lg[0], lg[1], lg[2], lg[3]);
                lo[1] = make_float4(lg[4], lg[5], lg[6], lg[7]);

                int i0 = 0; float v0 = lg[0];
                #pragma unroll
                for (int e = 1; e < NE; ++e)
                    if (lg[e] > v0) { v0 = lg[e]; i0 = e; }
                int i1 = -1; float v1 = -3.4e38f;
                #pragma unroll
                for (int e = 0; e < NE; ++e)
                    if (e != i0 && lg[e] > v1) { v1 = lg[e]; i1 = e; }

                const float w0 = 1.f / (1.f + expf(v1 - v0));
                wslot[tok * 2]     = w0;
                wslot[tok * 2 + 1] = 1.f - w0;
                route[tok] = i0 | (i1 << 8);
            }
        }
    }
}

// ---------------------------------------------------------------------------
// Route/bucket: LDS-aggregated histogram; 8 global atomics per block.
// ---------------------------------------------------------------------------
__global__ __launch_bounds__(1024)
void route_kernel(const int* __restrict__ route,
                  int* __restrict__ counts,
                  int* __restrict__ bucket)
{
    __shared__ int lcnt[NE];
    __shared__ int lbase[NE];
    const int tid = threadIdx.x;
    const int tok = blockIdx.x * 1024 + tid;

    if (tid < NE) lcnt[tid] = 0;
    __syncthreads();

    const int rt = route[tok];
    const int i0 = rt & 255;
    const int i1 = rt >> 8;
    const int r0 = atomicAdd(&lcnt[i0], 1);
    const int r1 = atomicAdd(&lcnt[i1], 1);
    __syncthreads();

    if (tid < NE) lbase[tid] = atomicAdd(&counts[tid], lcnt[tid]);
    __syncthreads();

    bucket[i0 * B_TOK + lbase[i0] + r0] = tok * 2;
    bucket[i1 * B_TOK + lbase[i1] + r1] = tok * 2 + 1;
}

// ---------------------------------------------------------------------------
// Prefix: cbase[e] = row base; cpad[e] = count padded to 128.
// ---------------------------------------------------------------------------
__global__ void prefix_kernel(const int* __restrict__ counts,
                              int* __restrict__ cbase)
{
    if (threadIdx.x == 0 && blockIdx.x == 0) {
        int acc = 0;
        for (int e = 0; e < NE; ++e) {
            const int cp = ((counts[e] + 127) >> 7) << 7;
            cbase[e]      = acc;
            cbase[NE + e] = cp;
            acc += cp;
        }
    }
}

// ---------------------------------------------------------------------------
// invfill: inv[entry] = global P row for each bucket slot.
// ---------------------------------------------------------------------------
__global__ __launch_bounds__(256)
void invfill_kernel(const int* __restrict__ bucket,
                    const int* __restrict__ counts,
                    const int* __restrict__ cbase,
                    int* __restrict__ inv)
{
    const int e   = blockIdx.x & 7;
    const int pos = (blockIdx.x >> 3) * 256 + threadIdx.x;
    if (pos < counts[e]) inv[bucket[e * B_TOK + pos]] = cbase[e] + pos;
}

// ---------------------------------------------------------------------------
// Expert MFMA (full-f-half blocks on 64-pos tiles — X-traffic-minimizing):
// block = (e, f-half fh (256 f), 64-pos tile); 256 thr / 4 waves;
// wave fg = w owns f rows [fg*64, fg*64+64) x all 64 pos; acc 2m x 2n =
// 64 VGPR -> launch_bounds(256,4) gives 4 blocks/CU (21 KB LDS).
// X is read ONCE per fh (256 MB total chip-wide, was 512 MB in r11);
// W demand (1 GB) is XCD-L2-resident (2 MB/expert, e = blockIdx&7 pin).
// r11's proven skeleton: per K-step (BK=32) stage [4 A linear gload_lds16
// + 1 B full-line chunk-XOR gather per thread] -> __syncthreads ->
// 8 ds_read + 8 MFMA/wave -> __syncthreads. Deterministic P2 partials.
// ---------------------------------------------------------------------------
__global__ __launch_bounds__(256, 4)
void expert_mfma_kernel(const unsigned short* __restrict__ xb,
                        const unsigned short* __restrict__ W1h,
                        const float* __restrict__ b1,
                        const float* __restrict__ W2,
                        const int* __restrict__ counts,
                        const int* __restrict__ cbase,
                        const int* __restrict__ bucket,
                        float* __restrict__ P2)
{
    const int e  = blockIdx.x & 7;
    const int r  = blockIdx.x >> 3;
    const int fh = r & 1;
    const int pt = r >> 1;
    const int n  = counts[e];
    const int pos0 = pt * 64;
    if (pos0 >= n) return;
    const int nt = min(64, n - pos0);
    const int cb = cbase[e];

    __shared__ unsigned short Ab[8192];   // [slot4][f'256][j8]  16 KB
    __shared__ unsigned short Bb[2048];   // [row64][c4][j8]      4 KB
    __shared__ float o_part[4][64];       // 1 KB

    const int tid = threadIdx.x;
    const int fg  = tid >> 6;    // wave = f-group (64 f)
    const int l   = tid & 63;
    const int lo5 = l & 31;
    const int hi  = l >> 5;

    const unsigned short* Aimg = W1h + (size_t)((e * 2 + fh) * 64) * 8192;

    // B gather: thread tid -> unit (row = tid>>2, c = tid&3); source chunk
    // pre-XORed (c ^ (row&3)) so the read-side XOR retrieves k-chunks.
    // 4 consecutive lanes cover one 64 B row-chunk -> full-line requests.
    const int brow = tid >> 2;
    const int bc   = tid & 3;
    const int btok = bucket[e * B_TOK + min(pos0 + brow, n - 1)] >> 1;
    const unsigned short* bsrc = xb + (size_t)btok * H_DIM + ((bc ^ (brow & 3)) * 8);
    const int bo = tid * 8;

    facc acc00, acc01, acc10, acc11;   // [m][nb]
    #pragma unroll
    for (int q = 0; q < 16; ++q) {
        acc00[q] = 0.f; acc01[q] = 0.f; acc10[q] = 0.f; acc11[q] = 0.f;
    }

    const int o0 = tid * 8, o1 = (256 + tid) * 8,
              o2 = (512 + tid) * 8, o3 = (768 + tid) * 8;

    for (int kk = 0; kk < NKSTEP; ++kk) {
        // stage A: 16 KB linear (4 gload_lds16/thread) + B: 1 gather load
        const unsigned short* as = Aimg + (size_t)kk * 8192;
        gload_lds16(as + o0, Ab + o0);
        gload_lds16(as + o1, Ab + o1);
        gload_lds16(as + o2, Ab + o2);
        gload_lds16(as + o3, Ab + o3);
        gload_lds16(bsrc + kk * BK, Bb + bo);
        __syncthreads();   // compiler drains vmcnt: tiles visible

        #pragma unroll
        for (int ks = 0; ks < 2; ++ks) {
            const int slot = ks * 2 + hi;
            const bfrag a0 = *reinterpret_cast<const bfrag*>(
                &Ab[(slot * 256 + fg * 64 + lo5) * 8]);
            const bfrag a1 = *reinterpret_cast<const bfrag*>(
                &Ab[(slot * 256 + fg * 64 + 32 + lo5) * 8]);
            const int row0 = lo5,      c0 = slot ^ (row0 & 3);
            const int row1 = 32 + lo5, c1 = slot ^ (row1 & 3);
            const bfrag b0  = *reinterpret_cast<const bfrag*>(
                &Bb[(row0 * 4 + c0) * 8]);
            const bfrag b1v = *reinterpret_cast<const bfrag*>(
                &Bb[(row1 * 4 + c1) * 8]);
            acc00 = __builtin_amdgcn_mfma_f32_32x32x16_bf16(a0, b0,  acc00, 0, 0, 0);
            acc01 = __builtin_amdgcn_mfma_f32_32x32x16_bf16(a0, b1v, acc01, 0, 0, 0);
            acc10 = __builtin_amdgcn_mfma_f32_32x32x16_bf16(a1, b0,  acc10, 0, 0, 0);
            acc11 = __builtin_amdgcn_mfma_f32_32x32x16_bf16(a1, b1v, acc11, 0, 0, 0);
        }
        __syncthreads();   // reads retired before next overwrite
    }

    // Epilogue: bias + exact GELU + W2 dot; reduce over this wave's 64 f,
    // then across the 4 waves via o_part.
    const float* b1e = b1 + e * HFD + fh * 256 + fg * 64;
    const float* W2e = W2 + e * HFD + fh * 256 + fg * 64;
    const float kInvSqrt2 = 0.70710678118654752f;

    float po0 = 0.f, po1 = 0.f;
    #pragma unroll
    for (int m = 0; m < 2; ++m) {
        const int base = m * 32 + 4 * hi;
        #pragma unroll
        for (int q = 0; q < 16; ++q) {
            const int frow = base + (q & 3) + 8 * (q >> 2);
            const float bv = b1e[frow];
            const float wv = W2e[frow];
            const float h0 = (m ? acc10[q] : acc00[q]) + bv;
            const float h1 = (m ? acc11[q] : acc01[q]) + bv;
            po0 += 0.5f * h0 * (1.f + erff(h0 * kInvSqrt2)) * wv;
            po1 += 0.5f * h1 * (1.f + erff(h1 * kInvSqrt2)) * wv;
        }
    }
    po0 += __shfl_xor(po0, 32, 64);
    po1 += __shfl_xor(po1, 32, 64);

    if (hi == 0) {
        o_part[fg][lo5]      = po0;
        o_part[fg][32 + lo5] = po1;
    }
    __syncthreads();

    if (tid < nt)
        P2[(size_t)fh * PROWS + cb + pos0 + tid] =
            (o_part[0][tid] + o_part[1][tid])
          + (o_part[2][tid] + o_part[3][tid]);
}

// ---------------------------------------------------------------------------
// Combine: out[t] = w0*(P2[0][g0]+P2[1][g0]) + w1*(...). Deterministic.
// ---------------------------------------------------------------------------
__global__ __launch_bounds__(256)
void combine_kernel(const int* __restrict__ inv,
                    const float* __restrict__ P2,
                    const float* __restrict__ wslot,
                    float* __restrict__ out_scores)
{
    const int t = blockIdx.x * 256 + threadIdx.x;
    if (t >= B_TOK) return;
    const int g0 = inv[2 * t];
    const int g1 = inv[2 * t + 1];
    const float s0 = P2[g0] + P2[PROWS + g0];
    const float s1 = P2[g1] + P2[PROWS + g1];
    out_scores[t] = wslot[2 * t] * s0 + wslot[2 * t + 1] * s1;
}

// ---------------------------------------------------------------------------
extern "C" void kernel_launch(void* const* d_in, const int* in_sizes, int n_in,
                              void* d_out, int out_size, void* d_ws, size_t ws_size,
                              hipStream_t stream)
{
    const float* x  = (const float*)d_in[0];
    const float* W1 = (const float*)d_in[1];
    const float* b1 = (const float*)d_in[2];
    const float* W2 = (const float*)d_in[3];
    const float* Wg = (const float*)d_in[4];
    const float* bg = (const float*)d_in[5];

    float* out        = (float*)d_out;
    float* out_scores = out;            // [B, 1]
    float* out_logits = out + B_TOK;    // [B, E]

    char* ws = (char*)d_ws;
    int*            counts = (int*)           (ws + OFF_COUNTS);
    int*            cbase  = (int*)           (ws + OFF_CBASE);
    int*            bucket = (int*)           (ws + OFF_BUCKET);
    float*          wslot  = (float*)         (ws + OFF_WSLOT);
    int*            route  = (int*)           (ws + OFF_ROUTE);
    int*            inv    = (int*)           (ws + OFF_INV);
    float*          WgT    = (float*)         (ws + OFF_WGT);
    float*          P2     = (float*)         (ws + OFF_P2);
    unsigned short* W1h    = (unsigned short*)(ws + OFF_W1H);
    unsigned short* xb     = (unsigned short*)(ws + OFF_XB);

    hipMemsetAsync(counts, 0, NE * sizeof(int), stream);

    wg_transpose_kernel<<<1, 256, 0, stream>>>(Wg, WgT);

    prep_w1_kernel<<<NE * NKSTEP, 256, 0, stream>>>(W1, W1h);

    gate_logits_kernel<<<B_TOK / 64, 256, 0, stream>>>(x, WgT, bg, out_logits,
                                                       wslot, route, xb);

    route_kernel<<<B_TOK / 1024, 1024, 0, stream>>>(route, counts, bucket);

    prefix_kernel<<<1, 64, 0, stream>>>(counts, cbase);

    invfill_kernel<<<NE * (B_TOK / 256), 256, 0, stream>>>(bucket, counts,
                                                           cbase, inv);

    expert_mfma_kernel<<<NE * 2 * PT64, 256, 0, stream>>>(
        xb, W1h, b1, W2, counts, cbase, bucket, P2);

    combine_kernel<<<B_TOK / 256, 256, 0, stream>>>(inv, P2, wslot, out_scores);
}